// Round 9
// baseline (29.383 us; speedup 1.0000x reference)
//
#include <hip/hip_runtime.h>
#include <math.h>

namespace {

constexpr int B_ = 4;
constexpr int N_ = 512;
constexpr int D_ = 256;
constexpr int L_ = 128;
constexpr int TI = 4;  // i-rows per dist block

// xs[b][l][n] = a[l] * sum_d x[b][n][d] * W[l][d]
// 1D grid, XCD-pinned: batch b runs on XCDs {2b, 2b+1} (blockIdx % 8 -> XCD).
// Block: 256 thr = 64 n x 4 l-groups x 4 l. W-tile and x-tile staged in LDS.
// (UNCHANGED from R8 for clean attribution.)
__global__ __launch_bounds__(256) void proj_kernel(
    const float* __restrict__ x, const float* __restrict__ W,
    const float* __restrict__ a, float* __restrict__ xs) {
  const int bid = blockIdx.x;       // 0..255
  const int xcd = bid & 7;          // round-robin XCD assignment
  const int b = xcd >> 1;           // batch pinned to XCD pair
  const int tile = ((xcd & 1) << 5) + (bid >> 3);  // 0..63
  const int l0 = (tile >> 3) * 16;
  const int n0 = (tile & 7) * 64;

  const int t = threadIdx.x;

  __shared__ float wl_s[16 * 256];  // 16 KB W tile
  __shared__ float xl[64 * 129];    // 33 KB x half-tile, pad 129 (conflict-free)

  const int n = t & 63;
  const int lg = t >> 6;  // 0..3, wave-uniform
  const float* __restrict__ xrow = xl + n * 129;

  // stage W tile (16 l x 256 d), coalesced float4
  {
    const float4* __restrict__ Wsrc =
        reinterpret_cast<const float4*>(W + (size_t)l0 * D_);
    float4* wdst = reinterpret_cast<float4*>(wl_s);
#pragma unroll
    for (int k = 0; k < 4; ++k) wdst[t + k * 256] = Wsrc[t + k * 256];
  }

  float acc[4] = {0.f, 0.f, 0.f, 0.f};

#pragma unroll
  for (int half = 0; half < 2; ++half) {
    __syncthreads();  // W ready (half 0) / protect x reuse (half 1)
    {
      const float4* __restrict__ xsrc = reinterpret_cast<const float4*>(
          x + ((size_t)(b * N_ + n0)) * D_ + half * 128);
#pragma unroll
      for (int k = 0; k < 8; ++k) {
        const int idx = t + k * 256;  // 0..2047
        const int sn = idx >> 5;      // local n
        const int sq = idx & 31;      // float4 within 128-chunk
        const float4 v = xsrc[(size_t)sn * 64 + sq];
        float* dst = xl + sn * 129 + sq * 4;
        dst[0] = v.x; dst[1] = v.y; dst[2] = v.z; dst[3] = v.w;
      }
    }
    __syncthreads();

    const float4* __restrict__ w4 = reinterpret_cast<const float4*>(wl_s);
#pragma unroll 4
    for (int d4 = 0; d4 < 32; ++d4) {
      const float x0 = xrow[d4 * 4 + 0];
      const float x1 = xrow[d4 * 4 + 1];
      const float x2 = xrow[d4 * 4 + 2];
      const float x3 = xrow[d4 * 4 + 3];
#pragma unroll
      for (int k = 0; k < 4; ++k) {
        const float4 w = w4[(lg * 4 + k) * 64 + half * 32 + d4];  // broadcast
        acc[k] += x0 * w.x + x1 * w.y + x2 * w.z + x3 * w.w;
      }
    }
  }

#pragma unroll
  for (int k = 0; k < 4; ++k) {
    const int l = l0 + lg * 4 + k;
    xs[((size_t)(b * L_ + l)) * N_ + n0 + n] = acc[k] * a[l];  // coalesced
  }
}

// Fused dist+softmax, XCD-pinned as R8. Main loop restructured for
// zero-VALU addressing: uniform SGPR pointers per l (compile-time const),
// lane offset j; LDS xi via offset-immediates; 16-deep xj reg prefetch.
__global__ __launch_bounds__(512) void dist_softmax_kernel(
    const float* __restrict__ xs, const float* __restrict__ adj,
    const int* __restrict__ box_num, const float* __restrict__ a,
    float* __restrict__ out) {
  const int bid = blockIdx.x;       // 0..511
  const int xcd = bid & 7;
  const int b = xcd >> 1;
  const int tile = ((xcd & 1) << 6) + (bid >> 3);  // 0..127
  const int i0 = tile * TI;

  const int t = threadIdx.x;
  const int j = t;
  const int bn = box_num[b];
  const float* __restrict__ xs_b = xs + (size_t)b * L_ * N_;

  __shared__ float xi_l[L_ * TI];  // [l][r], 2 KB, broadcast float4 reads
  __shared__ float red[8][TI];
  __shared__ float sa_l[2];
  __shared__ float rmax_s[TI];
  __shared__ float rsinv_s[TI];

  // stage i-rows: thread t -> (l = t>>2, r = t&3)
  xi_l[t] = xs_b[(t >> 2) * N_ + i0 + (t & 3)];

  // sum(a) prologue
  {
    float sa = (t < L_) ? a[t] : 0.f;
#pragma unroll
    for (int off = 1; off < 64; off <<= 1) sa += __shfl_xor(sa, off);
    if (t == 0) sa_l[0] = sa;
    if (t == 64) sa_l[1] = sa;
  }
  __syncthreads();
  const float sum_a = sa_l[0] + sa_l[1];

  float acc[TI];
#pragma unroll
  for (int r = 0; r < TI; ++r) acc[r] = 0.f;

  const float4* __restrict__ xi4 = reinterpret_cast<const float4*>(xi_l);
#pragma unroll
  for (int c = 0; c < 8; ++c) {  // 8 chunks x 16 l, fully unrolled
    float xj[16];
#pragma unroll
    for (int u = 0; u < 16; ++u) {
      // uniform (SGPR) base per l + lane offset j -> s-base global_load
      const float* __restrict__ pl = xs_b + (c * 16 + u) * N_;
      xj[u] = pl[j];
    }
#pragma unroll
    for (int u = 0; u < 16; ++u) {
      const float4 xi = xi4[c * 16 + u];  // ds_read_b128, offset-imm
      acc[0] += fabsf(xi.x - xj[u]);
      acc[1] += fabsf(xi.y - xj[u]);
      acc[2] += fabsf(xi.z - xj[u]);
      acc[3] += fabsf(xi.w - xj[u]);
    }
  }

  const bool vj = j < bn;
  float val[TI];
#pragma unroll
  for (int r = 0; r < TI; ++r) {
    const bool vi = (i0 + r) < bn;
    const float d = acc[r] - ((vi && vj) ? 0.f : sum_a);  // + mask*sum(a)
    val[r] = d >= 0.f ? d : 0.01f * d;                    // leaky_relu
  }

  const int lane = t & 63;
  const int wid = t >> 6;

  // ---- row max over 512 j ----
  {
    float wm[TI];
#pragma unroll
    for (int r = 0; r < TI; ++r) {
      float m = val[r];
#pragma unroll
      for (int off = 1; off < 64; off <<= 1) m = fmaxf(m, __shfl_xor(m, off));
      wm[r] = m;
    }
    if (lane == 0) {
#pragma unroll
      for (int r = 0; r < TI; ++r) red[wid][r] = wm[r];
    }
  }
  __syncthreads();
  if (t < TI) {
    float m = red[0][t];
#pragma unroll
    for (int w = 1; w < 8; ++w) m = fmaxf(m, red[w][t]);
    rmax_s[t] = m;
  }
  __syncthreads();

  float e[TI];
  const float* __restrict__ adjp = adj + ((size_t)(b * N_ + i0)) * N_ + j;
#pragma unroll
  for (int r = 0; r < TI; ++r) {
    e[r] = adjp[(size_t)r * N_] * __expf(val[r] - rmax_s[r]);
  }

  // ---- row sum over 512 j ----
  {
    float wsum[TI];
#pragma unroll
    for (int r = 0; r < TI; ++r) {
      float s = e[r];
#pragma unroll
      for (int off = 1; off < 64; off <<= 1) s += __shfl_xor(s, off);
      wsum[r] = s;
    }
    if (lane == 0) {
#pragma unroll
      for (int r = 0; r < TI; ++r) red[wid][r] = wsum[r];
    }
  }
  __syncthreads();
  if (t < TI) {
    float s = red[0][t];
#pragma unroll
    for (int w = 1; w < 8; ++w) s += red[w][t];
    rsinv_s[t] = 1.0f / s;
  }
  __syncthreads();

  float* __restrict__ op = out + ((size_t)(b * N_ + i0)) * N_ + j;
#pragma unroll
  for (int r = 0; r < TI; ++r) {
    op[(size_t)r * N_] = e[r] * rsinv_s[r] + 1e-10f;
  }
}

}  // namespace

extern "C" void kernel_launch(void* const* d_in, const int* in_sizes, int n_in,
                              void* d_out, int out_size, void* d_ws,
                              size_t ws_size, hipStream_t stream) {
  const float* x = (const float*)d_in[0];    // (B,N,D) f32
  const float* adj = (const float*)d_in[1];  // (B,N,N) f32
  const int* box_num = (const int*)d_in[2];  // (B,1) int32
  const float* W = (const float*)d_in[3];    // (L,D) f32
  const float* a = (const float*)d_in[4];    // (L,) f32
  float* out = (float*)d_out;                // (B,N,N) f32
  float* xs = (float*)d_ws;                  // B*L*N floats = 1 MB scratch

  proj_kernel<<<256, 256, 0, stream>>>(x, W, a, xs);
  dist_softmax_kernel<<<512, 512, 0, stream>>>(xs, adj, box_num, a, out);
}